// Round 3
// baseline (518.808 us; speedup 1.0000x reference)
//
#include <hip/hip_runtime.h>
#include <hip/hip_bf16.h>
#include <math.h>
#include <stdint.h>

typedef __bf16 bf16_t;
typedef __bf16 bf16x4 __attribute__((ext_vector_type(4)));
typedef __bf16 bf16x8 __attribute__((ext_vector_type(8)));
typedef float  f32x4  __attribute__((ext_vector_type(4)));

#define BATCH   4096
#define DM      1024
#define DFF     2048
#define NTILES  8
#define MAXXB   40   // max compacted x-blocks: 32 + 7 partials

__device__ __forceinline__ float gelu_exact(float x) {
    return 0.5f * x * (1.0f + erff(x * 0.70710678118654752440f));
}

__device__ __forceinline__ void async_ld16(const bf16_t* g, bf16_t* l) {
    __builtin_amdgcn_global_load_lds(
        (const __attribute__((address_space(1))) void*)g,
        (__attribute__((address_space(3))) void*)l, 16, 0, 0);
}

__device__ __forceinline__ f32x4 mfma16(bf16x8 a, bf16x8 b, f32x4 c) {
    return __builtin_amdgcn_mfma_f32_16x16x32_bf16(a, b, c, 0, 0, 0);
}

// ---------------- fused prep: x hi/lo split + 4 weight transposes ----------------
// tconv tile: 64k x 32n per block; reads coalesced rows, writes 16B/lane.
template<bool LO>
__device__ void tconv_body(const float* __restrict__ src, bf16_t* __restrict__ outh,
                           bf16_t* __restrict__ outl, int K, int N, int kt, int nt,
                           float (*t)[33]) {
    int n0 = nt * 32, k0 = kt * 64;
    int tx = threadIdx.x & 31, ty = threadIdx.x >> 5;
#pragma unroll
    for (int s = 0; s < 8; ++s)
        t[ty + 8 * s][tx] = src[(size_t)(k0 + ty + 8 * s) * N + (n0 + tx)];  // t[k][n]
    __syncthreads();
    int n = threadIdx.x >> 3, kc = (threadIdx.x & 7) * 8;
    float v[8]; bf16x8 h;
#pragma unroll
    for (int i = 0; i < 8; ++i) { v[i] = t[kc + i][n]; h[i] = (bf16_t)v[i]; }
    size_t oi = (size_t)(n0 + n) * K + k0 + kc;
    *(bf16x8*)(outh + oi) = h;
    if constexpr (LO) {
        bf16x8 l;
#pragma unroll
        for (int i = 0; i < 8; ++i) l[i] = (bf16_t)(v[i] - (float)h[i]);
        *(bf16x8*)(outl + oi) = l;
    }
}

#define NCVT 4096                       // BATCH*DM/4/256
#define NSQ  512                        // (1024/64)*(1024/32)
#define NBIG 8192                       // 8 mats * 1024 tiles
#define PREP_GRID (NCVT + NSQ + NSQ + NBIG + NBIG)

__global__ __launch_bounds__(256) void prep_kernel(
    const float* __restrict__ x, const float* __restrict__ Wr1, const float* __restrict__ Wo,
    const float* __restrict__ W1, const float* __restrict__ W2,
    bf16_t* __restrict__ xh, bf16_t* __restrict__ xl,
    bf16_t* __restrict__ Wr1h, bf16_t* __restrict__ Wr1l, bf16_t* __restrict__ Wot,
    bf16_t* __restrict__ W1t, bf16_t* __restrict__ W2t) {
    __shared__ float t[64][33];
    int b = blockIdx.x;
    if (b < NCVT) {                     // x -> hi/lo bf16 split
        int i = b * 256 + threadIdx.x;  // float4 index
        float4 v = ((const float4*)x)[i];
        bf16x4 h, l;
        float f;
        f = v.x; h[0] = (bf16_t)f; l[0] = (bf16_t)(f - (float)h[0]);
        f = v.y; h[1] = (bf16_t)f; l[1] = (bf16_t)(f - (float)h[1]);
        f = v.z; h[2] = (bf16_t)f; l[2] = (bf16_t)(f - (float)h[2]);
        f = v.w; h[3] = (bf16_t)f; l[3] = (bf16_t)(f - (float)h[3]);
        *(bf16x4*)(xh + (size_t)i * 4) = h;
        *(bf16x4*)(xl + (size_t)i * 4) = l;
        return;
    }
    b -= NCVT;
    if (b < NSQ) { tconv_body<true >(Wr1, Wr1h, Wr1l, DM, DM, b >> 5, b & 31, t); return; }
    b -= NSQ;
    if (b < NSQ) { tconv_body<false>(Wo, Wot, nullptr, DM, DM, b >> 5, b & 31, t); return; }
    b -= NSQ;
    if (b < NBIG) {                     // W1: (1024k, 2048n) -> 16 kt x 64 nt per mat
        int mat = b >> 10, r = b & 1023;
        size_t off = (size_t)mat * DM * DFF;
        tconv_body<false>(W1 + off, W1t + off, nullptr, DM, DFF, r >> 6, r & 63, t);
        return;
    }
    b -= NBIG;
    {                                   // W2: (2048k, 1024n) -> 32 kt x 32 nt per mat
        int mat = b >> 10, r = b & 1023;
        size_t off = (size_t)mat * DM * DFF;
        tconv_body<false>(W2 + off, W2t + off, nullptr, DFF, DM, r >> 5, r & 31, t);
    }
}

// ---------------- routing plan: compact (tile, xblock) list ----------------
__global__ void plan_kernel(const int* __restrict__ counts,
                            int* __restrict__ plan, int* __restrict__ ntotal) {
    if (threadIdx.x == 0) {
        int b = 0;
        for (int t = 0; t < NTILES; ++t) {
            int nb = (counts[t] + 127) >> 7;
            for (int i = 0; i < nb; ++i) plan[b++] = (t << 16) | i;
        }
        *ntotal = b;
    }
}

// ---------------- GEMM: C[M,N] = A[M,K] @ Bt[N,K]^T (+bias, opt gelu) ----------------
// 128x128 tile, BK=32, 4 waves (2x2), global_load_lds width-16 staging,
// explicit 2-stage LDS double-buffer: prefetch k+32 into other buffer right after
// the (single) per-iteration barrier, so the barrier's vmcnt(0) drain lands after
// a full 16-MFMA body instead of right after issue. One barrier per K-step.
template<bool SPLIT, bool GATHER, bool GELU, bool SCATTER, bool OUTF32>
__global__ __launch_bounds__(256) void gemm_kernel(
    const bf16_t* __restrict__ A, const bf16_t* __restrict__ Alo,
    const bf16_t* __restrict__ Bt, const bf16_t* __restrict__ Btlo,
    const float* __restrict__ bias,
    float* __restrict__ outF, bf16_t* __restrict__ outB,
    const int* __restrict__ perm, const int* __restrict__ counts,
    const int* __restrict__ plan, const int* __restrict__ ntotal,
    int M, int N, int K) {
    int tile, rb, cnt = M;
    const int* permT = nullptr;
    if constexpr (GATHER) {
        if ((int)blockIdx.x >= *ntotal) return;
        int p = plan[blockIdx.x];
        tile = p >> 16;
        rb = (p & 0xffff) * 128;
        cnt = counts[tile];
        permT = perm + tile * BATCH;
    } else {
        tile = blockIdx.z;
        rb = blockIdx.x * 128;
    }
    Bt   += (size_t)tile * K * N;
    if constexpr (SPLIT) Btlo += (size_t)tile * K * N;
    bias += (size_t)tile * N;

    constexpr int BUF = 128 * 32;
    __shared__ __align__(16) bf16_t As[2 * BUF];
    __shared__ __align__(16) bf16_t Bs[2 * BUF];
    __shared__ __align__(16) bf16_t Asl[SPLIT ? 2 * BUF : 8];
    __shared__ __align__(16) bf16_t Bsl[SPLIT ? 2 * BUF : 8];

    const int lane = threadIdx.x & 63;
    const int wave = threadIdx.x >> 6;
    const int wm = wave & 1, wn = wave >> 1;
    const int nb = blockIdx.y * 128;

    size_t aoff[2], boff[2];
#pragma unroll
    for (int r = 0; r < 2; ++r) {
        int seg = r * 4 + wave;
        int row = seg * 16 + (lane & 15);
        int col = (lane >> 4) * 8;
        int arow;
        if constexpr (GATHER) {
            int pos = rb + row;
            if (pos > cnt - 1) pos = cnt - 1;
            arow = permT[pos];
        } else {
            arow = rb + row;
        }
        aoff[r] = (size_t)arow * K + col;
        boff[r] = (size_t)(nb + row) * K + col;
    }

    f32x4 acc[4][4];
#pragma unroll
    for (int i = 0; i < 4; ++i)
#pragma unroll
        for (int j = 0; j < 4; ++j) acc[i][j] = (f32x4){0.f, 0.f, 0.f, 0.f};

    const int lr = lane & 15, lq = lane >> 4;
    const int rdoff = (lq * 16 + lr) * 8;   // element offset within 16-row segment

    auto stage = [&](int k0, int buf) {
#pragma unroll
        for (int r = 0; r < 2; ++r) {
            int seg = r * 4 + wave;
            async_ld16(A  + aoff[r] + k0, &As[buf * BUF + seg * 512]);
            async_ld16(Bt + boff[r] + k0, &Bs[buf * BUF + seg * 512]);
            if constexpr (SPLIT) {
                async_ld16(Alo  + aoff[r] + k0, &Asl[buf * BUF + seg * 512]);
                async_ld16(Btlo + boff[r] + k0, &Bsl[buf * BUF + seg * 512]);
            }
        }
    };

    stage(0, 0);
    int cur = 0;
    for (int k0 = 0; k0 < K; k0 += 32, cur ^= 1) {
        __syncthreads();                 // drains vmcnt: buf[cur] ready
        if (k0 + 32 < K) stage(k0 + 32, cur ^ 1);

        const bf16_t* as = As + cur * BUF;
        const bf16_t* bs = Bs + cur * BUF;
        bf16x8 af[4], bfr[4], afl[4], bfl[4];
#pragma unroll
        for (int i = 0; i < 4; ++i) {
            af[i]  = *(const bf16x8*)&as[(wm * 4 + i) * 512 + rdoff];
            bfr[i] = *(const bf16x8*)&bs[(wn * 4 + i) * 512 + rdoff];
            if constexpr (SPLIT) {
                afl[i] = *(const bf16x8*)&Asl[cur * BUF + (wm * 4 + i) * 512 + rdoff];
                bfl[i] = *(const bf16x8*)&Bsl[cur * BUF + (wn * 4 + i) * 512 + rdoff];
            }
        }
#pragma unroll
        for (int i = 0; i < 4; ++i)
#pragma unroll
            for (int j = 0; j < 4; ++j) {
                acc[i][j] = mfma16(af[i], bfr[j], acc[i][j]);
                if constexpr (SPLIT) {
                    // hi*lo cross terms; lo*lo is ~1e-4 absolute, below tolerance
                    acc[i][j] = mfma16(af[i], bfl[j], acc[i][j]);
                    acc[i][j] = mfma16(afl[i], bfr[j], acc[i][j]);
                }
            }
    }

    // epilogue: C row = (lane>>4)*4 + reg, col = lane&15 (m89/m91-verified)
#pragma unroll
    for (int i = 0; i < 4; ++i) {
#pragma unroll
        for (int j = 0; j < 4; ++j) {
#pragma unroll
            for (int r = 0; r < 4; ++r) {
                int m = wm * 64 + i * 16 + lq * 4 + r;
                int n = wn * 64 + j * 16 + lr;
                int pos = rb + m;
                if constexpr (GATHER) { if (pos >= cnt) continue; }
                int grow;
                if constexpr (SCATTER) grow = permT[pos];
                else                   grow = pos;
                int gn = nb + n;
                float v = acc[i][j][r] + bias[gn];
                if constexpr (GELU) v = gelu_exact(v);
                if constexpr (OUTF32) outF[(size_t)grow * N + gn] = v;
                else                  outB[(size_t)grow * N + gn] = (bf16_t)v;
            }
        }
    }
}

// ---------------- router layer2 + argmax + routing lists ----------------
__global__ __launch_bounds__(256) void router2_kernel(
    const float* __restrict__ Hr, const float* __restrict__ Wr2, const float* __restrict__ br2,
    float* __restrict__ outLog, float* __restrict__ outIdx,
    int* __restrict__ counts, int* __restrict__ perm) {
    int lane = threadIdx.x & 63, wave = threadIdx.x >> 6;
    int row = blockIdx.x * 4 + wave;
    const float* h = Hr + (size_t)row * DM;
    float acc[8];
#pragma unroll
    for (int j = 0; j < 8; ++j) acc[j] = 0.f;
    for (int k = lane; k < DM; k += 64) {
        float hv = h[k];
        const float4* w = (const float4*)(Wr2 + (size_t)k * 8);
        float4 w0 = w[0], w1 = w[1];
        acc[0] += hv * w0.x; acc[1] += hv * w0.y; acc[2] += hv * w0.z; acc[3] += hv * w0.w;
        acc[4] += hv * w1.x; acc[5] += hv * w1.y; acc[6] += hv * w1.z; acc[7] += hv * w1.w;
    }
#pragma unroll
    for (int off = 32; off; off >>= 1)
#pragma unroll
        for (int j = 0; j < 8; ++j) acc[j] += __shfl_down(acc[j], off);
    if (lane == 0) {
        float best = -1e30f; int bi = 0;
        float lg[8];
#pragma unroll
        for (int j = 0; j < 8; ++j) {
            float v = (acc[j] + br2[j]) * 2.0f;   // /TEMPERATURE, T=0.5
            lg[j] = v;
            if (v > best) { best = v; bi = j; }   // strict > == first-max (jnp.argmax)
        }
#pragma unroll
        for (int j = 0; j < 8; ++j) outLog[(size_t)row * 8 + j] = lg[j];
        outIdx[row] = (float)bi;
        int p = atomicAdd(&counts[bi], 1);
        perm[bi * BATCH + p] = row;
    }
}

// ---------------- host launch ----------------
extern "C" void kernel_launch(void* const* d_in, const int* in_sizes, int n_in,
                              void* d_out, int out_size, void* d_ws, size_t ws_size,
                              hipStream_t stream) {
    const float* x   = (const float*)d_in[0];
    const float* Wr1 = (const float*)d_in[1];
    const float* br1 = (const float*)d_in[2];
    const float* Wr2 = (const float*)d_in[3];
    const float* br2 = (const float*)d_in[4];
    const float* W1  = (const float*)d_in[5];
    const float* b1  = (const float*)d_in[6];
    const float* W2  = (const float*)d_in[7];
    const float* b2  = (const float*)d_in[8];
    const float* Wo  = (const float*)d_in[9];
    const float* bo  = (const float*)d_in[10];

    char* ws = (char*)d_ws;
    size_t o = 0;
    auto carve = [&](size_t bytes) { char* p = ws + o; o = (o + bytes + 255) & ~(size_t)255; return p; };
    bf16_t* Wr1h = (bf16_t*)carve((size_t)DM * DM * 2);
    bf16_t* Wr1l = (bf16_t*)carve((size_t)DM * DM * 2);
    bf16_t* Wot  = (bf16_t*)carve((size_t)DM * DM * 2);
    bf16_t* W1t  = (bf16_t*)carve((size_t)NTILES * DM * DFF * 2);
    bf16_t* W2t  = (bf16_t*)carve((size_t)NTILES * DM * DFF * 2);
    bf16_t* xh   = (bf16_t*)carve((size_t)BATCH * DM * 2);
    bf16_t* xl   = (bf16_t*)carve((size_t)BATCH * DM * 2);
    bf16_t* H1   = (bf16_t*)carve((size_t)BATCH * DFF * 2);
    bf16_t* sel  = (bf16_t*)carve((size_t)BATCH * DM * 2);
    float*  Hr   = (float*)carve((size_t)BATCH * DM * 4);
    int*    counts = (int*)carve(NTILES * sizeof(int));
    int*    perm   = (int*)carve((size_t)NTILES * BATCH * sizeof(int));
    int*    plan   = (int*)carve(MAXXB * sizeof(int));
    int*    ntotal = (int*)carve(sizeof(int));

    float* outMain = (float*)d_out;
    float* outIdx  = outMain + (size_t)BATCH * DM;
    float* outLog  = outIdx + BATCH;

    hipMemsetAsync(counts, 0, NTILES * sizeof(int), stream);

    prep_kernel<<<PREP_GRID, 256, 0, stream>>>(x, Wr1, Wo, W1, W2,
                                               xh, xl, Wr1h, Wr1l, Wot, W1t, W2t);

    // router layer 1: Hr = gelu(x @ Wr1 + br1), hi/lo split for fp32-class accuracy
    gemm_kernel<true, false, true, false, true><<<dim3(BATCH / 128, DM / 128, 1), 256, 0, stream>>>(
        xh, xl, Wr1h, Wr1l, br1, Hr, nullptr, nullptr, nullptr, nullptr, nullptr, BATCH, DM, DM);

    router2_kernel<<<BATCH / 4, 256, 0, stream>>>(Hr, Wr2, br2, outLog, outIdx, counts, perm);
    plan_kernel<<<1, 64, 0, stream>>>(counts, plan, ntotal);

    // expert layer 1: H1[token] = gelu(x[token] @ W1[t] + b1[t]), gathered+scattered
    gemm_kernel<false, true, true, true, false><<<dim3(MAXXB, DFF / 128, 1), 256, 0, stream>>>(
        xh, nullptr, W1t, nullptr, b1, nullptr, H1, perm, counts, plan, ntotal, BATCH, DFF, DM);

    // expert layer 2: sel[token] = H1[token] @ W2[t] + b2[t]
    gemm_kernel<false, true, false, true, false><<<dim3(MAXXB, DM / 128, 1), 256, 0, stream>>>(
        H1, nullptr, W2t, nullptr, b2, nullptr, sel, perm, counts, plan, ntotal, BATCH, DM, DFF);

    // output projection: out = sel @ Wo + bo
    gemm_kernel<false, false, false, false, true><<<dim3(BATCH / 128, DM / 128, 1), 256, 0, stream>>>(
        sel, nullptr, Wot, nullptr, bo, outMain, nullptr, nullptr, nullptr, nullptr, nullptr, BATCH, DM, DM);
}

// Round 4
// 444.157 us; speedup vs baseline: 1.1681x; 1.1681x over previous
//
#include <hip/hip_runtime.h>
#include <hip/hip_bf16.h>
#include <math.h>
#include <stdint.h>

typedef __bf16 bf16_t;
typedef __bf16 bf16x4 __attribute__((ext_vector_type(4)));
typedef __bf16 bf16x8 __attribute__((ext_vector_type(8)));
typedef float  f32x4  __attribute__((ext_vector_type(4)));

#define BATCH   4096
#define DM      1024
#define DFF     2048
#define NTILES  8
#define MAXXB   40   // max compacted x-blocks: 32 + 7 partials

__device__ __forceinline__ float gelu_exact(float x) {
    return 0.5f * x * (1.0f + erff(x * 0.70710678118654752440f));
}

__device__ __forceinline__ void async_ld16(const bf16_t* g, bf16_t* l) {
    __builtin_amdgcn_global_load_lds(
        (const __attribute__((address_space(1))) void*)g,
        (__attribute__((address_space(3))) void*)l, 16, 0, 0);
}

__device__ __forceinline__ f32x4 mfma16(bf16x8 a, bf16x8 b, f32x4 c) {
    return __builtin_amdgcn_mfma_f32_16x16x32_bf16(a, b, c, 0, 0, 0);
}

// ---------------- fused prep: x hi/lo split + 4 weight transposes ----------------
template<bool LO>
__device__ void tconv_body(const float* __restrict__ src, bf16_t* __restrict__ outh,
                           bf16_t* __restrict__ outl, int K, int N, int kt, int nt,
                           float (*t)[33]) {
    int n0 = nt * 32, k0 = kt * 64;
    int tx = threadIdx.x & 31, ty = threadIdx.x >> 5;
#pragma unroll
    for (int s = 0; s < 8; ++s)
        t[ty + 8 * s][tx] = src[(size_t)(k0 + ty + 8 * s) * N + (n0 + tx)];  // t[k][n]
    __syncthreads();
    int n = threadIdx.x >> 3, kc = (threadIdx.x & 7) * 8;
    float v[8]; bf16x8 h;
#pragma unroll
    for (int i = 0; i < 8; ++i) { v[i] = t[kc + i][n]; h[i] = (bf16_t)v[i]; }
    size_t oi = (size_t)(n0 + n) * K + k0 + kc;
    *(bf16x8*)(outh + oi) = h;
    if constexpr (LO) {
        bf16x8 l;
#pragma unroll
        for (int i = 0; i < 8; ++i) l[i] = (bf16_t)(v[i] - (float)h[i]);
        *(bf16x8*)(outl + oi) = l;
    }
}

#define NCVT 4096                       // BATCH*DM/4/256
#define NSQ  512                        // (1024/64)*(1024/32)
#define NBIG 8192                       // 8 mats * 1024 tiles
#define PREP_GRID (NCVT + NSQ + NSQ + NBIG + NBIG)

__global__ __launch_bounds__(256) void prep_kernel(
    const float* __restrict__ x, const float* __restrict__ Wr1, const float* __restrict__ Wo,
    const float* __restrict__ W1, const float* __restrict__ W2,
    bf16_t* __restrict__ xh, bf16_t* __restrict__ xl,
    bf16_t* __restrict__ Wr1h, bf16_t* __restrict__ Wr1l, bf16_t* __restrict__ Wot,
    bf16_t* __restrict__ W1t, bf16_t* __restrict__ W2t) {
    __shared__ float t[64][33];
    int b = blockIdx.x;
    if (b < NCVT) {                     // x -> hi/lo bf16 split
        int i = b * 256 + threadIdx.x;  // float4 index
        float4 v = ((const float4*)x)[i];
        bf16x4 h, l;
        float f;
        f = v.x; h[0] = (bf16_t)f; l[0] = (bf16_t)(f - (float)h[0]);
        f = v.y; h[1] = (bf16_t)f; l[1] = (bf16_t)(f - (float)h[1]);
        f = v.z; h[2] = (bf16_t)f; l[2] = (bf16_t)(f - (float)h[2]);
        f = v.w; h[3] = (bf16_t)f; l[3] = (bf16_t)(f - (float)h[3]);
        *(bf16x4*)(xh + (size_t)i * 4) = h;
        *(bf16x4*)(xl + (size_t)i * 4) = l;
        return;
    }
    b -= NCVT;
    if (b < NSQ) { tconv_body<true >(Wr1, Wr1h, Wr1l, DM, DM, b >> 5, b & 31, t); return; }
    b -= NSQ;
    if (b < NSQ) { tconv_body<false>(Wo, Wot, nullptr, DM, DM, b >> 5, b & 31, t); return; }
    b -= NSQ;
    if (b < NBIG) {                     // W1: (1024k, 2048n)
        int mat = b >> 10, r = b & 1023;
        size_t off = (size_t)mat * DM * DFF;
        tconv_body<false>(W1 + off, W1t + off, nullptr, DM, DFF, r >> 6, r & 63, t);
        return;
    }
    b -= NBIG;
    {                                   // W2: (2048k, 1024n)
        int mat = b >> 10, r = b & 1023;
        size_t off = (size_t)mat * DM * DFF;
        tconv_body<false>(W2 + off, W2t + off, nullptr, DFF, DM, r >> 5, r & 31, t);
    }
}

// ---------------- routing plan: compact (tile, xblock) list ----------------
__global__ void plan_kernel(const int* __restrict__ counts,
                            int* __restrict__ plan, int* __restrict__ ntotal) {
    if (threadIdx.x == 0) {
        int b = 0;
        for (int t = 0; t < NTILES; ++t) {
            int nb = (counts[t] + 127) >> 7;
            for (int i = 0; i < nb; ++i) plan[b++] = (t << 16) | i;
        }
        *ntotal = b;
    }
}

// ---------------- GEMM: C[M,N] = A[M,K] @ Bt[N,K]^T (+bias, opt gelu) ----------------
// 128x128 tile, BK=32, 4 waves (2x2), global_load_lds width-16 staging.
// Staging map (XOR swizzle): lane -> row = lane>>2 (4 lanes cover one 64B line:
// coalesced), chunk = (lane&3) ^ ((lane>>2)&3). LDS slot s of row r holds chunk
// s ^ (r&3); frag read for (row=lr, kchunk=lq) at slot lq^(lr&3) -> 8-lane LDS
// phases are <=2-way bank aliased (free), global reads fully coalesced.
// Non-SPLIT: 2-stage LDS double-buffer (32KB), one barrier/iter.
// SPLIT: single buffer (32KB total incl. lo buffers), two barriers/iter.
template<bool SPLIT, bool GATHER, bool GELU, bool SCATTER, bool OUTF32>
__global__ __launch_bounds__(256) void gemm_kernel(
    const bf16_t* __restrict__ A, const bf16_t* __restrict__ Alo,
    const bf16_t* __restrict__ Bt, const bf16_t* __restrict__ Btlo,
    const float* __restrict__ bias,
    float* __restrict__ outF, bf16_t* __restrict__ outB,
    const int* __restrict__ perm, const int* __restrict__ counts,
    const int* __restrict__ plan, const int* __restrict__ ntotal,
    int M, int N, int K) {
    int tile, rb, cnt = M;
    const int* permT = nullptr;
    if constexpr (GATHER) {
        if ((int)blockIdx.x >= *ntotal) return;
        int p = plan[blockIdx.x];
        tile = p >> 16;
        rb = (p & 0xffff) * 128;
        cnt = counts[tile];
        permT = perm + tile * BATCH;
    } else {
        tile = blockIdx.z;
        rb = blockIdx.x * 128;
    }
    Bt   += (size_t)tile * K * N;
    if constexpr (SPLIT) Btlo += (size_t)tile * K * N;
    bias += (size_t)tile * N;

    constexpr int BUF = 128 * 32;
    __shared__ __align__(16) bf16_t As[SPLIT ? BUF : 2 * BUF];
    __shared__ __align__(16) bf16_t Bs[SPLIT ? BUF : 2 * BUF];
    __shared__ __align__(16) bf16_t Asl[SPLIT ? BUF : 8];
    __shared__ __align__(16) bf16_t Bsl[SPLIT ? BUF : 8];

    const int lane = threadIdx.x & 63;
    const int wave = threadIdx.x >> 6;
    const int wm = wave & 1, wn = wave >> 1;
    const int nb = blockIdx.y * 128;

    // staging source offsets (XOR-swizzled chunk, coalesced rows)
    const int srow = lane >> 2;                                // row within 16-row segment
    const int scol = ((lane & 3) ^ (srow & 3)) * 8;            // swizzled k-chunk
    size_t aoff[2], boff[2];
#pragma unroll
    for (int r = 0; r < 2; ++r) {
        int seg = r * 4 + wave;
        int row = seg * 16 + srow;
        int arow;
        if constexpr (GATHER) {
            int pos = rb + row;
            if (pos > cnt - 1) pos = cnt - 1;
            arow = permT[pos];
        } else {
            arow = rb + row;
        }
        aoff[r] = (size_t)arow * K + scol;
        boff[r] = (size_t)(nb + row) * K + scol;
    }

    f32x4 acc[4][4];
#pragma unroll
    for (int i = 0; i < 4; ++i)
#pragma unroll
        for (int j = 0; j < 4; ++j) acc[i][j] = (f32x4){0.f, 0.f, 0.f, 0.f};

    const int lr = lane & 15, lq = lane >> 4;
    const int rdoff = (lr * 4 + (lq ^ (lr & 3))) * 8;          // swizzled frag offset (elements)

    auto stage = [&](int k0, int buf) {
#pragma unroll
        for (int r = 0; r < 2; ++r) {
            int seg = r * 4 + wave;
            async_ld16(A  + aoff[r] + k0, &As[buf * BUF + seg * 512]);
            async_ld16(Bt + boff[r] + k0, &Bs[buf * BUF + seg * 512]);
            if constexpr (SPLIT) {
                async_ld16(Alo  + aoff[r] + k0, &Asl[seg * 512]);
                async_ld16(Btlo + boff[r] + k0, &Bsl[seg * 512]);
            }
        }
    };

    auto compute = [&](const bf16_t* as, const bf16_t* bs) {
        bf16x8 af[4], bfr[4], afl[4], bfl[4];
#pragma unroll
        for (int i = 0; i < 4; ++i) {
            af[i]  = *(const bf16x8*)&as[(wm * 4 + i) * 512 + rdoff];
            bfr[i] = *(const bf16x8*)&bs[(wn * 4 + i) * 512 + rdoff];
            if constexpr (SPLIT) {
                afl[i] = *(const bf16x8*)&Asl[(wm * 4 + i) * 512 + rdoff];
                bfl[i] = *(const bf16x8*)&Bsl[(wn * 4 + i) * 512 + rdoff];
            }
        }
#pragma unroll
        for (int i = 0; i < 4; ++i)
#pragma unroll
            for (int j = 0; j < 4; ++j) {
                acc[i][j] = mfma16(af[i], bfr[j], acc[i][j]);
                if constexpr (SPLIT) {
                    // hi*lo cross terms; lo*lo ~1e-6, dropped
                    acc[i][j] = mfma16(af[i], bfl[j], acc[i][j]);
                    acc[i][j] = mfma16(afl[i], bfr[j], acc[i][j]);
                }
            }
    };

    if constexpr (SPLIT) {
        for (int k0 = 0; k0 < K; k0 += 32) {
            stage(k0, 0);
            __syncthreads();
            compute(As, Bs);
            __syncthreads();
        }
    } else {
        stage(0, 0);
        int cur = 0;
        for (int k0 = 0; k0 < K; k0 += 32, cur ^= 1) {
            __syncthreads();                 // drains vmcnt: buf[cur] ready
            if (k0 + 32 < K) stage(k0 + 32, cur ^ 1);
            compute(As + cur * BUF, Bs + cur * BUF);
        }
    }

    // epilogue: C row = (lane>>4)*4 + reg, col = lane&15 (m89/m91-verified)
#pragma unroll
    for (int i = 0; i < 4; ++i) {
#pragma unroll
        for (int j = 0; j < 4; ++j) {
#pragma unroll
            for (int r = 0; r < 4; ++r) {
                int m = wm * 64 + i * 16 + lq * 4 + r;
                int n = wn * 64 + j * 16 + lr;
                int pos = rb + m;
                if constexpr (GATHER) { if (pos >= cnt) continue; }
                int grow;
                if constexpr (SCATTER) grow = permT[pos];
                else                   grow = pos;
                int gn = nb + n;
                float v = acc[i][j][r] + bias[gn];
                if constexpr (GELU) v = gelu_exact(v);
                if constexpr (OUTF32) outF[(size_t)grow * N + gn] = v;
                else                  outB[(size_t)grow * N + gn] = (bf16_t)v;
            }
        }
    }
}

// ---------------- router layer2 + argmax + routing lists ----------------
__global__ __launch_bounds__(256) void router2_kernel(
    const float* __restrict__ Hr, const float* __restrict__ Wr2, const float* __restrict__ br2,
    float* __restrict__ outLog, float* __restrict__ outIdx,
    int* __restrict__ counts, int* __restrict__ perm) {
    int lane = threadIdx.x & 63, wave = threadIdx.x >> 6;
    int row = blockIdx.x * 4 + wave;
    const float* h = Hr + (size_t)row * DM;
    float acc[8];
#pragma unroll
    for (int j = 0; j < 8; ++j) acc[j] = 0.f;
    for (int k = lane; k < DM; k += 64) {
        float hv = h[k];
        const float4* w = (const float4*)(Wr2 + (size_t)k * 8);
        float4 w0 = w[0], w1 = w[1];
        acc[0] += hv * w0.x; acc[1] += hv * w0.y; acc[2] += hv * w0.z; acc[3] += hv * w0.w;
        acc[4] += hv * w1.x; acc[5] += hv * w1.y; acc[6] += hv * w1.z; acc[7] += hv * w1.w;
    }
#pragma unroll
    for (int off = 32; off; off >>= 1)
#pragma unroll
        for (int j = 0; j < 8; ++j) acc[j] += __shfl_down(acc[j], off);
    if (lane == 0) {
        float best = -1e30f; int bi = 0;
        float lg[8];
#pragma unroll
        for (int j = 0; j < 8; ++j) {
            float v = (acc[j] + br2[j]) * 2.0f;   // /TEMPERATURE, T=0.5
            lg[j] = v;
            if (v > best) { best = v; bi = j; }   // strict > == first-max (jnp.argmax)
        }
#pragma unroll
        for (int j = 0; j < 8; ++j) outLog[(size_t)row * 8 + j] = lg[j];
        outIdx[row] = (float)bi;
        int p = atomicAdd(&counts[bi], 1);
        perm[bi * BATCH + p] = row;
    }
}

// ---------------- host launch ----------------
extern "C" void kernel_launch(void* const* d_in, const int* in_sizes, int n_in,
                              void* d_out, int out_size, void* d_ws, size_t ws_size,
                              hipStream_t stream) {
    const float* x   = (const float*)d_in[0];
    const float* Wr1 = (const float*)d_in[1];
    const float* br1 = (const float*)d_in[2];
    const float* Wr2 = (const float*)d_in[3];
    const float* br2 = (const float*)d_in[4];
    const float* W1  = (const float*)d_in[5];
    const float* b1  = (const float*)d_in[6];
    const float* W2  = (const float*)d_in[7];
    const float* b2  = (const float*)d_in[8];
    const float* Wo  = (const float*)d_in[9];
    const float* bo  = (const float*)d_in[10];

    char* ws = (char*)d_ws;
    size_t o = 0;
    auto carve = [&](size_t bytes) { char* p = ws + o; o = (o + bytes + 255) & ~(size_t)255; return p; };
    bf16_t* Wr1h = (bf16_t*)carve((size_t)DM * DM * 2);
    bf16_t* Wr1l = (bf16_t*)carve((size_t)DM * DM * 2);
    bf16_t* Wot  = (bf16_t*)carve((size_t)DM * DM * 2);
    bf16_t* W1t  = (bf16_t*)carve((size_t)NTILES * DM * DFF * 2);
    bf16_t* W2t  = (bf16_t*)carve((size_t)NTILES * DM * DFF * 2);
    bf16_t* xh   = (bf16_t*)carve((size_t)BATCH * DM * 2);
    bf16_t* xl   = (bf16_t*)carve((size_t)BATCH * DM * 2);
    bf16_t* H1   = (bf16_t*)carve((size_t)BATCH * DFF * 2);
    bf16_t* sel  = (bf16_t*)carve((size_t)BATCH * DM * 2);
    float*  Hr   = (float*)carve((size_t)BATCH * DM * 4);
    int*    counts = (int*)carve(NTILES * sizeof(int));
    int*    perm   = (int*)carve((size_t)NTILES * BATCH * sizeof(int));
    int*    plan   = (int*)carve(MAXXB * sizeof(int));
    int*    ntotal = (int*)carve(sizeof(int));

    float* outMain = (float*)d_out;
    float* outIdx  = outMain + (size_t)BATCH * DM;
    float* outLog  = outIdx + BATCH;

    hipMemsetAsync(counts, 0, NTILES * sizeof(int), stream);

    prep_kernel<<<PREP_GRID, 256, 0, stream>>>(x, Wr1, Wo, W1, W2,
                                               xh, xl, Wr1h, Wr1l, Wot, W1t, W2t);

    // router layer 1: Hr = gelu(x @ Wr1 + br1), hi/lo split for fp32-class accuracy
    gemm_kernel<true, false, true, false, true><<<dim3(BATCH / 128, DM / 128, 1), 256, 0, stream>>>(
        xh, xl, Wr1h, Wr1l, br1, Hr, nullptr, nullptr, nullptr, nullptr, nullptr, BATCH, DM, DM);

    router2_kernel<<<BATCH / 4, 256, 0, stream>>>(Hr, Wr2, br2, outLog, outIdx, counts, perm);
    plan_kernel<<<1, 64, 0, stream>>>(counts, plan, ntotal);

    // expert layer 1: H1[token] = gelu(x[token] @ W1[t] + b1[t]), gathered+scattered
    gemm_kernel<false, true, true, true, false><<<dim3(MAXXB, DFF / 128, 1), 256, 0, stream>>>(
        xh, nullptr, W1t, nullptr, b1, nullptr, H1, perm, counts, plan, ntotal, BATCH, DFF, DM);

    // expert layer 2: sel[token] = H1[token] @ W2[t] + b2[t]
    gemm_kernel<false, true, false, true, false><<<dim3(MAXXB, DM / 128, 1), 256, 0, stream>>>(
        H1, nullptr, W2t, nullptr, b2, nullptr, sel, perm, counts, plan, ntotal, BATCH, DM, DFF);

    // output projection: out = sel @ Wo + bo
    gemm_kernel<false, false, false, false, true><<<dim3(BATCH / 128, DM / 128, 1), 256, 0, stream>>>(
        sel, nullptr, Wot, nullptr, bo, outMain, nullptr, nullptr, nullptr, nullptr, nullptr, BATCH, DM, DM);
}

// Round 6
// 442.129 us; speedup vs baseline: 1.1734x; 1.0046x over previous
//
#include <hip/hip_runtime.h>
#include <hip/hip_bf16.h>
#include <math.h>
#include <stdint.h>

typedef __bf16 bf16_t;
typedef __bf16 bf16x4 __attribute__((ext_vector_type(4)));
typedef __bf16 bf16x8 __attribute__((ext_vector_type(8)));
typedef float  f32x4  __attribute__((ext_vector_type(4)));

#define BATCH   4096
#define DM      1024
#define DFF     2048
#define NTILES  8
#define MAXXB   40   // max compacted x-blocks: 32 + 7 partials

__device__ __forceinline__ float gelu_exact(float x) {
    return 0.5f * x * (1.0f + erff(x * 0.70710678118654752440f));
}

__device__ __forceinline__ void async_ld16(const bf16_t* g, bf16_t* l) {
    __builtin_amdgcn_global_load_lds(
        (const __attribute__((address_space(1))) void*)g,
        (__attribute__((address_space(3))) void*)l, 16, 0, 0);
}

__device__ __forceinline__ f32x4 mfma16(bf16x8 a, bf16x8 b, f32x4 c) {
    return __builtin_amdgcn_mfma_f32_16x16x32_bf16(a, b, c, 0, 0, 0);
}

// ---------------- fused prep: x hi/lo split + 4 weight transposes ----------------
// 64x64 tile transpose, float4 global loads, f4-XOR-swizzled LDS (no padding so
// 16B alignment holds; read-phase banks are 2-way = free), bf16x8 stores with
// 4 lanes covering a 128B-contiguous run of each output row.
template<bool LO>
__device__ void tconv64_body(const float* __restrict__ src, bf16_t* __restrict__ outh,
                             bf16_t* __restrict__ outl, int K, int N, int kt, int nt,
                             float4* t /* 64*16 float4 = 16KB */) {
    const int tid = threadIdx.x;
    const int k0 = kt * 64, n0 = nt * 64;
    // load: rows = k (64), cols = n (16 float4); lane c covers n0+4c..+3
#pragma unroll
    for (int p = 0; p < 4; ++p) {
        int row = p * 16 + (tid >> 4);
        int c = tid & 15;
        float4 v = *(const float4*)(src + (size_t)(k0 + row) * N + n0 + c * 4);
        t[row * 16 + (c ^ ((row >> 2) & 15))] = v;
    }
    __syncthreads();
    // read+convert: thread -> output row n = tid>>2, k chunk = 16*(tid&3)
    const int n = tid >> 2, b = tid & 3;
    const float* tf = (const float*)t;
    float v[16];
#pragma unroll
    for (int i = 0; i < 16; ++i) {
        int k = 16 * b + i;
        int f4 = k * 16 + ((n >> 2) ^ ((k >> 2) & 15));
        v[i] = tf[f4 * 4 + (n & 3)];
    }
    bf16x8 h0, h1;
#pragma unroll
    for (int i = 0; i < 8; ++i) { h0[i] = (bf16_t)v[i]; h1[i] = (bf16_t)v[8 + i]; }
    size_t oi = (size_t)(n0 + n) * K + k0 + 16 * b;
    *(bf16x8*)(outh + oi) = h0;
    *(bf16x8*)(outh + oi + 8) = h1;
    if constexpr (LO) {
        bf16x8 l0, l1;
#pragma unroll
        for (int i = 0; i < 8; ++i) {
            l0[i] = (bf16_t)(v[i] - (float)h0[i]);
            l1[i] = (bf16_t)(v[8 + i] - (float)h1[i]);
        }
        *(bf16x8*)(outl + oi) = l0;
        *(bf16x8*)(outl + oi + 8) = l1;
    }
}

#define NCVT2 2048                      // BATCH*DM/8/256
#define NSQ64 256                       // (1024/64)^2
#define NW1   4096                      // 8 mats * (1024/64)*(2048/64)
#define NW2   4096
#define PREP_GRID (NCVT2 + NSQ64 + NSQ64 + NW1 + NW2)

__global__ __launch_bounds__(256) void prep_kernel(
    const float* __restrict__ x, const float* __restrict__ Wr1, const float* __restrict__ Wo,
    const float* __restrict__ W1, const float* __restrict__ W2,
    bf16_t* __restrict__ xh, bf16_t* __restrict__ xl,
    bf16_t* __restrict__ Wr1h, bf16_t* __restrict__ Wr1l, bf16_t* __restrict__ Wot,
    bf16_t* __restrict__ W1t, bf16_t* __restrict__ W2t) {
    __shared__ float4 t[64 * 16];
    int b = blockIdx.x;
    if (b < NCVT2) {                    // x -> hi/lo bf16 split, 32B/lane
        size_t i = (size_t)b * 256 + threadIdx.x;   // 8-float group index
        const float4* x4 = (const float4*)x;
        float4 v0 = x4[2 * i], v1 = x4[2 * i + 1];
        float f[8] = {v0.x, v0.y, v0.z, v0.w, v1.x, v1.y, v1.z, v1.w};
        bf16x8 h, l;
#pragma unroll
        for (int j = 0; j < 8; ++j) { h[j] = (bf16_t)f[j]; l[j] = (bf16_t)(f[j] - (float)h[j]); }
        *(bf16x8*)(xh + i * 8) = h;
        *(bf16x8*)(xl + i * 8) = l;
        return;
    }
    b -= NCVT2;
    if (b < NSQ64) { tconv64_body<true >(Wr1, Wr1h, Wr1l, DM, DM, b >> 4, b & 15, t); return; }
    b -= NSQ64;
    if (b < NSQ64) { tconv64_body<false>(Wo, Wot, nullptr, DM, DM, b >> 4, b & 15, t); return; }
    b -= NSQ64;
    if (b < NW1) {                      // W1: src (1024k, 2048n) -> 16 kt x 32 nt
        int mat = b >> 9, r = b & 511;
        size_t off = (size_t)mat * DM * DFF;
        tconv64_body<false>(W1 + off, W1t + off, nullptr, DM, DFF, r >> 5, r & 31, t);
        return;
    }
    b -= NW1;
    {                                   // W2: src (2048k, 1024n) -> 32 kt x 16 nt
        int mat = b >> 9, r = b & 511;
        size_t off = (size_t)mat * DM * DFF;
        tconv64_body<false>(W2 + off, W2t + off, nullptr, DFF, DM, r >> 4, r & 15, t);
    }
}

// ---------------- routing plan: compact (tile, xblock) list ----------------
__global__ void plan_kernel(const int* __restrict__ counts,
                            int* __restrict__ plan, int* __restrict__ ntotal) {
    if (threadIdx.x == 0) {
        int b = 0;
        for (int t = 0; t < NTILES; ++t) {
            int nb = (counts[t] + 127) >> 7;
            for (int i = 0; i < nb; ++i) plan[b++] = (t << 16) | i;
        }
        *ntotal = b;
    }
}

// ---------------- GEMM: C[M,N] = A[M,K] @ Bt[N,K]^T (+bias, opt gelu) ----------------
// 128x128 tile, BK=32, 4 waves (2x2), global_load_lds width-16 staging.
// Staging map (XOR swizzle): lane -> row = lane>>2 (4 lanes cover one 64B line:
// coalesced), chunk = (lane&3) ^ ((lane>>2)&3). LDS slot s of row r holds chunk
// s ^ (r&3); frag read for (row=lr, kchunk=lq) at slot lq^(lr&3) -> 8-lane LDS
// phases are <=2-way bank aliased (free), global reads fully coalesced.
// Non-SPLIT: 2-stage LDS double-buffer (32KB), one barrier/iter.
// SPLIT: single buffer (32KB total incl. lo buffers), two barriers/iter.
template<bool SPLIT, bool GATHER, bool GELU, bool SCATTER, bool OUTF32>
__global__ __launch_bounds__(256) void gemm_kernel(
    const bf16_t* __restrict__ A, const bf16_t* __restrict__ Alo,
    const bf16_t* __restrict__ Bt, const bf16_t* __restrict__ Btlo,
    const float* __restrict__ bias,
    float* __restrict__ outF, bf16_t* __restrict__ outB,
    const int* __restrict__ perm, const int* __restrict__ counts,
    const int* __restrict__ plan, const int* __restrict__ ntotal,
    int M, int N, int K) {
    int tile, rb, cnt = M;
    const int* permT = nullptr;
    if constexpr (GATHER) {
        if ((int)blockIdx.x >= *ntotal) return;
        int p = plan[blockIdx.x];
        tile = p >> 16;
        rb = (p & 0xffff) * 128;
        cnt = counts[tile];
        permT = perm + tile * BATCH;
    } else {
        tile = blockIdx.z;
        rb = blockIdx.x * 128;
    }
    Bt   += (size_t)tile * K * N;
    if constexpr (SPLIT) Btlo += (size_t)tile * K * N;
    bias += (size_t)tile * N;

    constexpr int BUF = 128 * 32;
    __shared__ __align__(16) bf16_t As[SPLIT ? BUF : 2 * BUF];
    __shared__ __align__(16) bf16_t Bs[SPLIT ? BUF : 2 * BUF];
    __shared__ __align__(16) bf16_t Asl[SPLIT ? BUF : 8];
    __shared__ __align__(16) bf16_t Bsl[SPLIT ? BUF : 8];

    const int lane = threadIdx.x & 63;
    const int wave = threadIdx.x >> 6;
    const int wm = wave & 1, wn = wave >> 1;
    const int nb = blockIdx.y * 128;

    // staging source offsets (XOR-swizzled chunk, coalesced rows)
    const int srow = lane >> 2;                                // row within 16-row segment
    const int scol = ((lane & 3) ^ (srow & 3)) * 8;            // swizzled k-chunk
    size_t aoff[2], boff[2];
#pragma unroll
    for (int r = 0; r < 2; ++r) {
        int seg = r * 4 + wave;
        int row = seg * 16 + srow;
        int arow;
        if constexpr (GATHER) {
            int pos = rb + row;
            if (pos > cnt - 1) pos = cnt - 1;
            arow = permT[pos];
        } else {
            arow = rb + row;
        }
        aoff[r] = (size_t)arow * K + scol;
        boff[r] = (size_t)(nb + row) * K + scol;
    }

    f32x4 acc[4][4];
#pragma unroll
    for (int i = 0; i < 4; ++i)
#pragma unroll
        for (int j = 0; j < 4; ++j) acc[i][j] = (f32x4){0.f, 0.f, 0.f, 0.f};

    const int lr = lane & 15, lq = lane >> 4;
    const int rdoff = (lr * 4 + (lq ^ (lr & 3))) * 8;          // swizzled frag offset (elements)

    auto stage = [&](int k0, int buf) {
#pragma unroll
        for (int r = 0; r < 2; ++r) {
            int seg = r * 4 + wave;
            async_ld16(A  + aoff[r] + k0, &As[buf * BUF + seg * 512]);
            async_ld16(Bt + boff[r] + k0, &Bs[buf * BUF + seg * 512]);
            if constexpr (SPLIT) {
                async_ld16(Alo  + aoff[r] + k0, &Asl[seg * 512]);
                async_ld16(Btlo + boff[r] + k0, &Bsl[seg * 512]);
            }
        }
    };

    auto compute = [&](const bf16_t* as, const bf16_t* bs) {
        bf16x8 af[4], bfr[4], afl[4], bfl[4];
#pragma unroll
        for (int i = 0; i < 4; ++i) {
            af[i]  = *(const bf16x8*)&as[(wm * 4 + i) * 512 + rdoff];
            bfr[i] = *(const bf16x8*)&bs[(wn * 4 + i) * 512 + rdoff];
            if constexpr (SPLIT) {
                afl[i] = *(const bf16x8*)&Asl[(wm * 4 + i) * 512 + rdoff];
                bfl[i] = *(const bf16x8*)&Bsl[(wn * 4 + i) * 512 + rdoff];
            }
        }
#pragma unroll
        for (int i = 0; i < 4; ++i)
#pragma unroll
            for (int j = 0; j < 4; ++j) {
                acc[i][j] = mfma16(af[i], bfr[j], acc[i][j]);
                if constexpr (SPLIT) {
                    // hi*lo cross terms; lo*lo ~1e-6, dropped
                    acc[i][j] = mfma16(af[i], bfl[j], acc[i][j]);
                    acc[i][j] = mfma16(afl[i], bfr[j], acc[i][j]);
                }
            }
    };

    if constexpr (SPLIT) {
        for (int k0 = 0; k0 < K; k0 += 32) {
            stage(k0, 0);
            __syncthreads();
            compute(As, Bs);
            __syncthreads();
        }
    } else {
        stage(0, 0);
        int cur = 0;
        for (int k0 = 0; k0 < K; k0 += 32, cur ^= 1) {
            __syncthreads();                 // drains vmcnt: buf[cur] ready
            if (k0 + 32 < K) stage(k0 + 32, cur ^ 1);
            compute(As + cur * BUF, Bs + cur * BUF);
        }
    }

    // epilogue: C row = (lane>>4)*4 + reg, col = lane&15 (m89/m91-verified)
#pragma unroll
    for (int i = 0; i < 4; ++i) {
#pragma unroll
        for (int j = 0; j < 4; ++j) {
#pragma unroll
            for (int r = 0; r < 4; ++r) {
                int m = wm * 64 + i * 16 + lq * 4 + r;
                int n = wn * 64 + j * 16 + lr;
                int pos = rb + m;
                if constexpr (GATHER) { if (pos >= cnt) continue; }
                int grow;
                if constexpr (SCATTER) grow = permT[pos];
                else                   grow = pos;
                int gn = nb + n;
                float v = acc[i][j][r] + bias[gn];
                if constexpr (GELU) v = gelu_exact(v);
                if constexpr (OUTF32) outF[(size_t)grow * N + gn] = v;
                else                  outB[(size_t)grow * N + gn] = (bf16_t)v;
            }
        }
    }
}

// ---------------- router layer2 + argmax + routing lists ----------------
__global__ __launch_bounds__(256) void router2_kernel(
    const float* __restrict__ Hr, const float* __restrict__ Wr2, const float* __restrict__ br2,
    float* __restrict__ outLog, float* __restrict__ outIdx,
    int* __restrict__ counts, int* __restrict__ perm) {
    int lane = threadIdx.x & 63, wave = threadIdx.x >> 6;
    int row = blockIdx.x * 4 + wave;
    const float* h = Hr + (size_t)row * DM;
    float acc[8];
#pragma unroll
    for (int j = 0; j < 8; ++j) acc[j] = 0.f;
    for (int k = lane; k < DM; k += 64) {
        float hv = h[k];
        const float4* w = (const float4*)(Wr2 + (size_t)k * 8);
        float4 w0 = w[0], w1 = w[1];
        acc[0] += hv * w0.x; acc[1] += hv * w0.y; acc[2] += hv * w0.z; acc[3] += hv * w0.w;
        acc[4] += hv * w1.x; acc[5] += hv * w1.y; acc[6] += hv * w1.z; acc[7] += hv * w1.w;
    }
#pragma unroll
    for (int off = 32; off; off >>= 1)
#pragma unroll
        for (int j = 0; j < 8; ++j) acc[j] += __shfl_down(acc[j], off);
    if (lane == 0) {
        float best = -1e30f; int bi = 0;
        float lg[8];
#pragma unroll
        for (int j = 0; j < 8; ++j) {
            float v = (acc[j] + br2[j]) * 2.0f;   // /TEMPERATURE, T=0.5
            lg[j] = v;
            if (v > best) { best = v; bi = j; }   // strict > == first-max (jnp.argmax)
        }
#pragma unroll
        for (int j = 0; j < 8; ++j) outLog[(size_t)row * 8 + j] = lg[j];
        outIdx[row] = (float)bi;
        int p = atomicAdd(&counts[bi], 1);
        perm[bi * BATCH + p] = row;
    }
}

// ---------------- host launch ----------------
extern "C" void kernel_launch(void* const* d_in, const int* in_sizes, int n_in,
                              void* d_out, int out_size, void* d_ws, size_t ws_size,
                              hipStream_t stream) {
    const float* x   = (const float*)d_in[0];
    const float* Wr1 = (const float*)d_in[1];
    const float* br1 = (const float*)d_in[2];
    const float* Wr2 = (const float*)d_in[3];
    const float* br2 = (const float*)d_in[4];
    const float* W1  = (const float*)d_in[5];
    const float* b1  = (const float*)d_in[6];
    const float* W2  = (const float*)d_in[7];
    const float* b2  = (const float*)d_in[8];
    const float* Wo  = (const float*)d_in[9];
    const float* bo  = (const float*)d_in[10];

    char* ws = (char*)d_ws;
    size_t o = 0;
    auto carve = [&](size_t bytes) { char* p = ws + o; o = (o + bytes + 255) & ~(size_t)255; return p; };
    bf16_t* Wr1h = (bf16_t*)carve((size_t)DM * DM * 2);
    bf16_t* Wr1l = (bf16_t*)carve((size_t)DM * DM * 2);
    bf16_t* Wot  = (bf16_t*)carve((size_t)DM * DM * 2);
    bf16_t* W1t  = (bf16_t*)carve((size_t)NTILES * DM * DFF * 2);
    bf16_t* W2t  = (bf16_t*)carve((size_t)NTILES * DM * DFF * 2);
    bf16_t* xh   = (bf16_t*)carve((size_t)BATCH * DM * 2);
    bf16_t* xl   = (bf16_t*)carve((size_t)BATCH * DM * 2);
    bf16_t* H1   = (bf16_t*)carve((size_t)BATCH * DFF * 2);
    bf16_t* sel  = (bf16_t*)carve((size_t)BATCH * DM * 2);
    float*  Hr   = (float*)carve((size_t)BATCH * DM * 4);
    int*    counts = (int*)carve(NTILES * sizeof(int));
    int*    perm   = (int*)carve((size_t)NTILES * BATCH * sizeof(int));
    int*    plan   = (int*)carve(MAXXB * sizeof(int));
    int*    ntotal = (int*)carve(sizeof(int));

    float* outMain = (float*)d_out;
    float* outIdx  = outMain + (size_t)BATCH * DM;
    float* outLog  = outIdx + BATCH;

    hipMemsetAsync(counts, 0, NTILES * sizeof(int), stream);

    prep_kernel<<<PREP_GRID, 256, 0, stream>>>(x, Wr1, Wo, W1, W2,
                                               xh, xl, Wr1h, Wr1l, Wot, W1t, W2t);

    // router layer 1: Hr = gelu(x @ Wr1 + br1), hi/lo split for fp32-class accuracy
    gemm_kernel<true, false, true, false, true><<<dim3(BATCH / 128, DM / 128, 1), 256, 0, stream>>>(
        xh, xl, Wr1h, Wr1l, br1, Hr, nullptr, nullptr, nullptr, nullptr, nullptr, BATCH, DM, DM);

    router2_kernel<<<BATCH / 4, 256, 0, stream>>>(Hr, Wr2, br2, outLog, outIdx, counts, perm);
    plan_kernel<<<1, 64, 0, stream>>>(counts, plan, ntotal);

    // expert layer 1: H1[token] = gelu(x[token] @ W1[t] + b1[t]), gathered+scattered
    gemm_kernel<false, true, true, true, false><<<dim3(MAXXB, DFF / 128, 1), 256, 0, stream>>>(
        xh, nullptr, W1t, nullptr, b1, nullptr, H1, perm, counts, plan, ntotal, BATCH, DFF, DM);

    // expert layer 2: sel[token] = H1[token] @ W2[t] + b2[t]
    gemm_kernel<false, true, false, true, false><<<dim3(MAXXB, DM / 128, 1), 256, 0, stream>>>(
        H1, nullptr, W2t, nullptr, b2, nullptr, sel, perm, counts, plan, ntotal, BATCH, DM, DFF);

    // output projection: out = sel @ Wo + bo
    gemm_kernel<false, false, false, false, true><<<dim3(BATCH / 128, DM / 128, 1), 256, 0, stream>>>(
        sel, nullptr, Wot, nullptr, bo, outMain, nullptr, nullptr, nullptr, nullptr, nullptr, BATCH, DM, DM);
}